// Round 1
// baseline (364.186 us; speedup 1.0000x reference)
//
#include <hip/hip_runtime.h>
#include <hip/hip_fp16.h>
#include <math.h>

// SpinSphericalBlock: separable spin-weighted SHT -> channel mix -> inverse SHT
// -> complex BN (spin0 mean, via Parseval on G) -> magnitude-ReLU gating.
//
// Constants: B=8, RES=64, RES_OUT=32, L=15, SPINS_IN=(0,1), SPINS_OUT=(0,1,2),
// C_IN=64, C_OUT=128, NM=31. Output: out_size=3,145,728 float32 = Re(y),
// (b,t,p,s,d) row-major (established R0-R4).
//
// R17 theory (post-mortem R16): block-splitting null -> kernel slack is NOT
// wave-count-limited. K3 re-reads the 6.3MB weight tensor 64x (402MB) from
// LLC (same-l k-blocks x 4 b-groups; slice doesn't fit per-XCD L2 under
// round-robin dispatch) -> ~30-40us, block-count-invariant. Fix:
//   * K1 packs kr/ki -> float4 W (6.3MB) in 48 spare blocks (hidden).
//   * K3: single-k x 4-b blocks, grid (256,2) x 192 thr -> 197MB traffic,
//     depth-2 prefetch (8 loads in flight).
//   * XCD-chunked k swizzle: k = 32*(bid&7)+(bid>>3); XCD g's l-slices
//     (0.8-2.3MB) fit its private 4MB L2 -> re-reads become L2 hits.
// K1/K2/K4/K5 structure and all interchange layouts unchanged.
//
//   K1 k_phi_tables: blocks<512: F[bt,m,iu] = sum_p x e^{-im phi_p} (radix-2)
//                    512..626: Wigner tables (fp64 recurrence) + zero stats
//                    627..674: pack weights into float4 W
//   K2 k_theta_in:   coeffs[b,k,iu]= sum_t A_in[i,k,t] F[b,t,m(k),iu]
//   K3 k_mix:        oc[b,k,sd]    = sum_iu coeffs * W[l(k),i,s,u,d]
//   K4 k_theta_out:  G[bt,m,sd]    = sum_l A_out[s,k,t] oc[b,k,sd]  + stats
//   K5 k_synth_final: y = BN(sum_m G e^{+im phi'_p}) -> gate -> Re(y) (radix-2)

#define PI_D 3.14159265358979323846

// ---------------- workspace layout (bytes) ----------------
#define OFF_A_IN    ((size_t)24320)     // 2*256*64 float    = 131072
#define OFF_A_OUT   ((size_t)155648)    // 3*256*32 float    = 98304
#define OFF_STATS   ((size_t)254208)    // 3*384 float       = 4608
#define OFF_R1      ((size_t)260608)    // F fp16 (8.1MB) then oc fp16 (3.1MB)
#define OFF_R2      ((size_t)25426688)  // coeffs fp16 (1MB) then G fp16 (12.2MB)
#define OFF_W       ((size_t)67108864)  // packed weights float4 (6.3MB)

// ln(j!) for j=0..30
__constant__ double LF[31] = {
    0.0, 0.0, 0.6931471805599453, 1.791759469228055, 3.1780538303479458,
    4.787491742782046, 6.579251212010101, 8.525161361065415,
    10.604602902745251, 12.801827480081469, 15.104412573075516,
    17.502307845873887, 19.987214495661885, 22.552163853123425,
    25.19122118273868, 27.89927138384089, 30.671860106080672,
    33.50507345013689, 36.39544520803305, 39.339884187199495,
    42.335616460753485, 45.38013889847691, 48.47118135183523,
    51.60667556776438, 54.78472939811232, 58.00360522298052,
    61.261701761002, 64.55753862700634, 67.88974313718154,
    71.25703896716801, 74.65823634883016};

__device__ inline int isqrt_k(int k) {
    int l = (int)sqrtf((float)k + 0.5f);
    while (l * l > k) --l;
    while ((l + 1) * (l + 1) <= k) ++l;
    return l;
}

// d^l_{m,n}(theta) via seed term (1 exp + 2 log) + exact ratio recurrence.
__device__ double wigner_d_rec(int l, int m, int n, double theta) {
    int an = n < 0 ? -n : n;
    int am = m < 0 ? -m : m;
    if (l < an || l < am) return 0.0;
    int kmin = max(0, n - m), kmax = min(l + n, l - m);
    if (kmax < kmin) return 0.0;
    double cb = cos(0.5 * theta), sb = sin(0.5 * theta);
    double pref = 0.5 * (LF[l + m] + LF[l - m] + LF[l + n] + LF[l - n]);
    double lterm = pref
        - (LF[l + n - kmin] + LF[kmin] + LF[m - n + kmin] + LF[l - m - kmin])
        + (double)(2 * l + n - m - 2 * kmin) * log(cb)
        + (double)(m - n + 2 * kmin) * log(sb);
    double term = exp(lterm);
    if ((m - n + kmin) & 1) term = -term;
    double r = (sb * sb) / (cb * cb);
    double acc = term;
    for (int k = kmin; k < kmax; ++k) {
        term *= -((double)((l + n - k) * (l - m - k)) * r)
                / ((double)((k + 1) * (m - n + k + 1)));
        acc += term;
    }
    return acc;
}

// K1: fused phi-DFT (blocks 0..511) + table generation (512..626)
//     + weight packing (627..674).
__global__ __launch_bounds__(512, 2) void k_phi_tables(const float* __restrict__ xr,
                                                       const float* __restrict__ xi,
                                                       __half2* __restrict__ F,
                                                       float* __restrict__ A_in,
                                                       float* __restrict__ A_out,
                                                       float* __restrict__ stats,
                                                       const float* __restrict__ kr,
                                                       const float* __restrict__ ki,
                                                       float4* __restrict__ W) {
    if (blockIdx.x >= 512) {
        if (blockIdx.x >= 627) {
            // pack kr/ki -> W[lis][u][dp] = (kr2d, kr2d+1, ki2d, ki2d+1)
            // 393,216 float4 over 48 blocks x 512 thr x 16 iters
            int e0 = (blockIdx.x - 627) * 512 + threadIdx.x;
            const float2* kr2 = (const float2*)kr;
            const float2* ki2 = (const float2*)ki;
#pragma unroll
            for (int j = 0; j < 16; ++j) {
                int e = e0 + j * 24576;
                int dp = e & 63, r = e >> 6;   // r = lis*64 + u, r < 6144
                float2 a = kr2[(size_t)r * 64 + dp];
                float2 b = ki2[(size_t)r * 64 + dp];
                W[e] = make_float4(a.x, a.y, b.x, b.y);
            }
            return;
        }
        int idx = (blockIdx.x - 512) * 512 + threadIdx.x;
        if (idx < 32768) {
            int t = idx & 63, k = (idx >> 6) & 255, i = idx >> 14;
            int l = isqrt_k(k);
            int m = k - l * l - l;
            double theta = ((double)t + 0.5) * PI_D / 64.0;
            double w = sin(theta) * (PI_D / 64.0) * (2.0 * PI_D / 64.0);
            double norm = sqrt((2.0 * l + 1.0) / (4.0 * PI_D));
            double d = wigner_d_rec(l, m, -i, theta);
            A_in[idx] = (float)(((m & 1) ? -1.0 : 1.0) * norm * w * d);
            return;
        }
        idx -= 32768;
        if (idx < 24576) {
            int t = idx & 31, k = (idx >> 5) & 255, s = idx >> 13;
            int l = isqrt_k(k);
            int m = k - l * l - l;
            double theta = ((double)t + 0.5) * PI_D / 32.0;
            double norm = sqrt((2.0 * l + 1.0) / (4.0 * PI_D));
            double d = wigner_d_rec(l, m, -s, theta);
            A_out[idx] = (float)(((m & 1) ? -1.0 : 1.0) * norm * d);
            return;
        }
        idx -= 24576;
        if (idx < 1152) stats[idx] = 0.f;
        return;
    }
    int bt = blockIdx.x;
    int iu = threadIdx.x & 127, mh = threadIdx.x >> 7;
    int mi0 = mh * 8;
    float2 acc[8], w[8], st[8];
#pragma unroll
    for (int j = 0; j < 8; ++j) {
        int m = mi0 + j - 15;
        float sy, sx;
        __sincosf(-(float)m * (float)(PI_D / 32.0), &sy, &sx);
        st[j] = make_float2(sx, sy);
        w[j] = make_float2(1.f, 0.f);
        acc[j] = make_float2(0.f, 0.f);
    }
    const float* xrb = xr + (size_t)bt * 8192 + iu;
    const float* xib = xi + (size_t)bt * 8192 + iu;
    for (int p = 0; p < 32; ++p) {
        float a  = xrb[(size_t)p * 128];
        float b  = xib[(size_t)p * 128];
        float a2 = xrb[(size_t)(p + 32) * 128];
        float b2 = xib[(size_t)(p + 32) * 128];
        float sar = a + a2, sai = b + b2;   // for even m
        float dar = a - a2, dai = b - b2;   // for odd m
#pragma unroll
        for (int j = 0; j < 8; ++j) {
            float ur = (j & 1) ? sar : dar;  // j odd -> m even
            float ui = (j & 1) ? sai : dai;
            acc[j].x += ur * w[j].x - ui * w[j].y;
            acc[j].y += ur * w[j].y + ui * w[j].x;
            float nx = w[j].x * st[j].x - w[j].y * st[j].y;
            w[j].y = w[j].x * st[j].y + w[j].y * st[j].x;
            w[j].x = nx;
        }
    }
    __half2* Fb = F + (size_t)bt * 31 * 128 + iu;
#pragma unroll
    for (int j = 0; j < 8; ++j) {
        int mi = mi0 + j;
        if (mi < 31) Fb[(size_t)mi * 128] = __float22half2_rn(acc[j]);
    }
}

// K2: theta contraction. grid (31, 8, 2) = (mi, b, iu-half); 256 threads =
// (iu_l 64) x (th 4). iu-half == spin index i, so only one A_in plane staged.
__global__ __launch_bounds__(256, 4) void k_theta_in(const __half2* __restrict__ F,
                                                     const float* __restrict__ A_in,
                                                     __half2* __restrict__ coeffs) {
    __shared__ float A[16][64];        // 4 KB, zero-padded below |m|
    __shared__ float2 red[2][16][64];  // 16 KB reduction buffer
    int mi = blockIdx.x, b = blockIdx.y, z = blockIdx.z;  // z = i
    int m = mi - 15;
    int am = m < 0 ? -m : m;
    int tid = threadIdx.x;
    for (int idx = tid; idx < 1024; idx += 256) {
        int j = idx >> 6, t = idx & 63;
        float v = 0.f;
        if (j >= am) v = A_in[((size_t)z * 256 + (j * j + j + m)) * 64 + t];
        A[j][t] = v;
    }
    __syncthreads();
    int iu_l = tid & 63, th = tid >> 6;
    int iu = z * 64 + iu_l;
    float2 acc[16];
#pragma unroll
    for (int j = 0; j < 16; ++j) acc[j] = make_float2(0.f, 0.f);
    const __half2* Fb = F + ((size_t)b * 64 * 31 + mi) * 128 + iu;
    for (int tt = 0; tt < 16; ++tt) {
        int t = th * 16 + tt;
        float2 f = __half22float2(Fb[(size_t)t * 31 * 128]);
#pragma unroll
        for (int j = 0; j < 16; ++j) {
            float a = A[j][t];
            acc[j].x += a * f.x;
            acc[j].y += a * f.y;
        }
    }
    if (th >= 2) {
#pragma unroll
        for (int j = 0; j < 16; ++j) red[th - 2][j][iu_l] = acc[j];
    }
    __syncthreads();
    if (th < 2) {
#pragma unroll
        for (int j = 0; j < 16; ++j) {
            float2 r = red[th][j][iu_l];
            acc[j].x += r.x;
            acc[j].y += r.y;
        }
    }
    __syncthreads();
    if (th == 1) {
#pragma unroll
        for (int j = 0; j < 16; ++j) red[0][j][iu_l] = acc[j];
    }
    __syncthreads();
    if (th == 0) {
#pragma unroll
        for (int j = 0; j < 16; ++j) {
            if (j >= am) {
                float2 r = red[0][j][iu_l];
                coeffs[((size_t)b * 256 + (j * j + j + m)) * 128 + iu] =
                    __float22half2_rn(make_float2(acc[j].x + r.x, acc[j].y + r.y));
            }
        }
    }
}

// K3: channel mix. grid (256, 2) = (k-swizzled, bq); 192 threads = (s 3)x(dp 64).
// Each block: 1 k x 4 b. XCD-chunked swizzle: XCD g = bid&7 owns k in
// [32g, 32g+32) so its l-slices (<=2.3MB) fit the private 4MB L2.
// Depth-2 software pipeline: 8 float4 weight loads in flight over the
// 32-FMA-per-iu compute.
__global__ __launch_bounds__(192, 4) void k_mix(const __half2* __restrict__ coeffs,
                                                const float4* __restrict__ W,
                                                __half2* __restrict__ oc) {
    __shared__ float2 cs[4][128];  // [bb][iu], 4 KB (wave-uniform reads: broadcast)
    int bx = blockIdx.x;
    int k = ((bx & 7) << 5) + (bx >> 3);  // XCD-chunked k
    int b0 = blockIdx.y * 4;
    int tid = threadIdx.x;
    for (int idx = tid; idx < 512; idx += 192) {
        int bb = idx >> 7, iu = idx & 127;
        cs[bb][iu] =
            __half22float2(coeffs[((size_t)(b0 + bb) * 256 + k) * 128 + iu]);
    }
    __syncthreads();
    int s = tid >> 6, dp = tid & 63;
    int l = isqrt_k(k);
    float2 acc[4][2];
#pragma unroll
    for (int bb = 0; bb < 4; ++bb) {
        acc[bb][0] = make_float2(0.f, 0.f);
        acc[bb][1] = make_float2(0.f, 0.f);
    }
    const float4* W0 = W + (size_t)(6 * l + s) * 4096 + dp;  // i=0 slice
    const float4* W1 = W0 + 3 * 4096;                        // i=1 slice
    float4 A[4], Bf[4];
#pragma unroll
    for (int j = 0; j < 4; ++j) {
        A[j]  = W0[(size_t)j * 64];
        Bf[j] = W0[(size_t)(j + 4) * 64];
    }
#pragma unroll
    for (int bp = 0; bp < 16; ++bp) {
        int base = bp * 8;
        float4 nA[4], nB[4];
        if (bp < 15) {
            int p0 = base + 8;       // multiple of 8, never straddles 64
            int p1 = p0 + 4;
            const float4* Pa = (p0 < 64) ? (W0 + (size_t)p0 * 64)
                                         : (W1 + (size_t)(p0 - 64) * 64);
            const float4* Pb = (p1 < 64) ? (W0 + (size_t)p1 * 64)
                                         : (W1 + (size_t)(p1 - 64) * 64);
#pragma unroll
            for (int j = 0; j < 4; ++j) {
                nA[j] = Pa[(size_t)j * 64];
                nB[j] = Pb[(size_t)j * 64];
            }
        }
#pragma unroll
        for (int j = 0; j < 4; ++j) {
            int iu = base + j;
            float2 wr = make_float2(A[j].x, A[j].y);
            float2 wi = make_float2(A[j].z, A[j].w);
#pragma unroll
            for (int bb = 0; bb < 4; ++bb) {
                float2 cv = cs[bb][iu];
                acc[bb][0].x += cv.x * wr.x - cv.y * wi.x;
                acc[bb][0].y += cv.x * wi.x + cv.y * wr.x;
                acc[bb][1].x += cv.x * wr.y - cv.y * wi.y;
                acc[bb][1].y += cv.x * wi.y + cv.y * wr.y;
            }
        }
#pragma unroll
        for (int j = 0; j < 4; ++j) {
            int iu = base + 4 + j;
            float2 wr = make_float2(Bf[j].x, Bf[j].y);
            float2 wi = make_float2(Bf[j].z, Bf[j].w);
#pragma unroll
            for (int bb = 0; bb < 4; ++bb) {
                float2 cv = cs[bb][iu];
                acc[bb][0].x += cv.x * wr.x - cv.y * wi.x;
                acc[bb][0].y += cv.x * wi.x + cv.y * wr.x;
                acc[bb][1].x += cv.x * wr.y - cv.y * wi.y;
                acc[bb][1].y += cv.x * wi.y + cv.y * wr.y;
            }
        }
        if (bp < 15) {
#pragma unroll
            for (int j = 0; j < 4; ++j) { A[j] = nA[j]; Bf[j] = nB[j]; }
        }
    }
#pragma unroll
    for (int bb = 0; bb < 4; ++bb) {
        size_t o = ((size_t)(b0 + bb) * 256 + k) * 384 + s * 128 + 2 * dp;
        oc[o]     = __float22half2_rn(acc[bb][0]);
        oc[o + 1] = __float22half2_rn(acc[bb][1]);
    }
}

// K4: theta expansion + stats. grid (31, 8, 2) = (mi, b, sd-half); 192 threads.
__global__ __launch_bounds__(192, 4) void k_theta_out(const __half2* __restrict__ oc,
                                                      const float* __restrict__ A_out,
                                                      __half2* __restrict__ G,
                                                      float* __restrict__ ssr,
                                                      float* __restrict__ ssi,
                                                      float* __restrict__ ssq) {
    __shared__ float Ao[3][16][32];  // 6KB
    int mi = blockIdx.x, b = blockIdx.y, z = blockIdx.z;
    int m = mi - 15;
    int am = m < 0 ? -m : m;
    int tid = threadIdx.x;
    for (int idx = tid; idx < 1536; idx += 192) {
        int s = idx >> 9, j = (idx >> 5) & 15, t = idx & 31;
        float v = 0.f;
        if (j >= am) v = A_out[((size_t)s * 256 + (j * j + j + m)) * 32 + t];
        Ao[s][j][t] = v;
    }
    __syncthreads();
    int sd = z * 192 + tid;
    int s = sd >> 7;
    float2 c[16];
#pragma unroll
    for (int j = 0; j < 16; ++j) {
        c[j] = make_float2(0.f, 0.f);
        if (j >= am)
            c[j] = __half22float2(oc[((size_t)b * 256 + (j * j + j + m)) * 384 + sd]);
    }
    float sq = 0.f, sr = 0.f, si = 0.f;
    for (int t = 0; t < 32; ++t) {
        float fr = 0.f, fi = 0.f;
#pragma unroll
        for (int j = 0; j < 16; ++j) {
            float a = Ao[s][j][t];
            fr += a * c[j].x;
            fi += a * c[j].y;
        }
        G[(((size_t)b * 32 + t) * 31 + mi) * 384 + sd] =
            __float22half2_rn(make_float2(fr, fi));
        sq += fr * fr + fi * fi;
        if (mi == 15) { sr += fr; si += fi; }
    }
    atomicAdd(&ssq[sd], sq);
    if (mi == 15) {
        atomicAdd(&ssr[sd], sr);
        atomicAdd(&ssi[sd], si);
    }
}

// K5: phi synthesis + BN + gate, radix-2 folded. grid (256 bt, 2 sd-half),
// 192 threads. Rotation state (g[31]+st[31]) in registers; (192,2) caps 256.
__global__ __launch_bounds__(192, 2) void k_synth_final(const __half2* __restrict__ G,
                                                        const float* __restrict__ ssr,
                                                        const float* __restrict__ ssi,
                                                        const float* __restrict__ ssq,
                                                        const float* __restrict__ gamma,
                                                        const float* __restrict__ betar,
                                                        const float* __restrict__ betai,
                                                        const float* __restrict__ bias,
                                                        float* __restrict__ out) {
    int bt = blockIdx.x;
    int sd = blockIdx.y * 192 + threadIdx.x;
    int s = sd >> 7;
    float2 g[31], st[31];
#pragma unroll
    for (int mi = 0; mi < 31; ++mi) {
        g[mi] = __half22float2(G[((size_t)bt * 31 + mi) * 384 + sd]);
        float sy, sx;
        __sincosf((float)(mi - 15) * (float)(PI_D / 16.0), &sy, &sx);
        st[mi] = make_float2(sx, sy);
    }
    const float invN = 1.0f / 256.0f;
    float mur = 0.f, mui = 0.f;
    if (s == 0) { mur = ssr[sd] * invN; mui = ssi[sd] * invN; }
    float var = ssq[sd] * invN - (mur * mur + mui * mui);
    float scale = gamma[sd] / sqrtf(var + 1e-5f);
    float br = (s == 0) ? betar[sd] : 0.f;
    float bi = (s == 0) ? betai[sd] : 0.f;
    float bb = bias[sd];
    float* ob = out + (size_t)bt * 32 * 384 + sd;
    for (int p = 0; p < 16; ++p) {
        float fr = 0.f, fi = 0.f, fr2 = 0.f, fi2 = 0.f;
#pragma unroll
        for (int mi = 0; mi < 31; ++mi) {
            fr += g[mi].x;
            fi += g[mi].y;
            if (mi & 1) { fr2 += g[mi].x; fi2 += g[mi].y; }  // m even
            else        { fr2 -= g[mi].x; fi2 -= g[mi].y; }  // m odd
        }
        {
            float yr = (fr - mur) * scale + br;
            float yi = (fi - mui) * scale + bi;
            float mag = sqrtf(yr * yr + yi * yi);
            float f = fmaxf(mag + bb, 0.f) / (mag + 1e-6f);
            ob[(size_t)p * 384] = yr * f;
        }
        {
            float yr = (fr2 - mur) * scale + br;
            float yi = (fi2 - mui) * scale + bi;
            float mag = sqrtf(yr * yr + yi * yi);
            float f = fmaxf(mag + bb, 0.f) / (mag + 1e-6f);
            ob[(size_t)(p + 16) * 384] = yr * f;
        }
#pragma unroll
        for (int mi = 0; mi < 31; ++mi) {
            float nx = g[mi].x * st[mi].x - g[mi].y * st[mi].y;
            g[mi].y = g[mi].x * st[mi].y + g[mi].y * st[mi].x;
            g[mi].x = nx;
        }
    }
}

extern "C" void kernel_launch(void* const* d_in, const int* in_sizes, int n_in,
                              void* d_out, int out_size, void* d_ws, size_t ws_size,
                              hipStream_t stream) {
    const float* xr    = (const float*)d_in[0];
    const float* xi    = (const float*)d_in[1];
    const float* kr    = (const float*)d_in[2];
    const float* ki    = (const float*)d_in[3];
    const float* gamma = (const float*)d_in[4];
    const float* betar = (const float*)d_in[5];
    const float* betai = (const float*)d_in[6];
    const float* bias  = (const float*)d_in[7];
    float* out = (float*)d_out;

    char* ws = (char*)d_ws;
    float*   A_in   = (float*)(ws + OFF_A_IN);
    float*   A_out  = (float*)(ws + OFF_A_OUT);
    float*   stats  = (float*)(ws + OFF_STATS);
    float*   ssr    = stats;
    float*   ssi    = stats + 384;
    float*   ssq    = stats + 768;
    __half2* F      = (__half2*)(ws + OFF_R1);  // then oc (fp16)
    __half2* oc     = (__half2*)(ws + OFF_R1);
    __half2* coeffs = (__half2*)(ws + OFF_R2);  // then G (fp16)
    __half2* G      = (__half2*)(ws + OFF_R2);
    float4*  W      = (float4*)(ws + OFF_W);

    k_phi_tables<<<675, 512, 0, stream>>>(xr, xi, F, A_in, A_out, stats, kr, ki, W);
    k_theta_in<<<dim3(31, 8, 2), 256, 0, stream>>>(F, A_in, coeffs);
    k_mix<<<dim3(256, 2), 192, 0, stream>>>(coeffs, W, oc);
    k_theta_out<<<dim3(31, 8, 2), 192, 0, stream>>>(oc, A_out, G, ssr, ssi, ssq);
    k_synth_final<<<dim3(256, 2), 192, 0, stream>>>(G, ssr, ssi, ssq,
                                                    gamma, betar, betai, bias, out);
}

// Round 2
// 179.481 us; speedup vs baseline: 2.0291x; 2.0291x over previous
//
#include <hip/hip_runtime.h>
#include <hip/hip_fp16.h>
#include <math.h>

// SpinSphericalBlock: separable spin-weighted SHT -> channel mix -> inverse SHT
// -> complex BN (spin0 mean, via Parseval on G) -> magnitude-ReLU gating.
//
// Constants: B=8, RES=64, RES_OUT=32, L=15, SPINS_IN=(0,1), SPINS_OUT=(0,1,2),
// C_IN=64, C_OUT=128, NM=31. Output: out_size=3,145,728 float32 = Re(y),
// (b,t,p,s,d) row-major (established R0-R4).
//
// R18 post-mortem of R17: k_mix regressed 250us with WRITE_SIZE=416MB at
// VGPR_Count=64 -> scratch spill storm (64 VGPRs of weight state + forced
// 16x unroll under launch_bounds(192,4)). Fix: depth-1 prefetch (cur[4]/
// nxt[4] float4 = 32 VGPRs in flight), launch_bounds(192,2) (cap 256),
// no forced outer unroll. Keep float4-packed W, 1k x 4b blocks, XCD swizzle.
//
//   K1 k_phi_tables: blocks<512: F[bt,m,iu] = sum_p x e^{-im phi_p} (radix-2)
//                    512..626: Wigner tables (fp64 recurrence) + zero stats
//                    627..674: pack weights into float4 W
//   K2 k_theta_in:   coeffs[b,k,iu]= sum_t A_in[i,k,t] F[b,t,m(k),iu]
//   K3 k_mix:        oc[b,k,sd]    = sum_iu coeffs * W[l(k),i,s,u,d]
//   K4 k_theta_out:  G[bt,m,sd]    = sum_l A_out[s,k,t] oc[b,k,sd]  + stats
//   K5 k_synth_final: y = BN(sum_m G e^{+im phi'_p}) -> gate -> Re(y) (radix-2)

#define PI_D 3.14159265358979323846

// ---------------- workspace layout (bytes) ----------------
#define OFF_A_IN    ((size_t)24320)     // 2*256*64 float    = 131072
#define OFF_A_OUT   ((size_t)155648)    // 3*256*32 float    = 98304
#define OFF_STATS   ((size_t)254208)    // 3*384 float       = 4608
#define OFF_R1      ((size_t)260608)    // F fp16 (8.1MB) then oc fp16 (3.1MB)
#define OFF_R2      ((size_t)25426688)  // coeffs fp16 (1MB) then G fp16 (12.2MB)
#define OFF_W       ((size_t)67108864)  // packed weights float4 (6.3MB)

// ln(j!) for j=0..30
__constant__ double LF[31] = {
    0.0, 0.0, 0.6931471805599453, 1.791759469228055, 3.1780538303479458,
    4.787491742782046, 6.579251212010101, 8.525161361065415,
    10.604602902745251, 12.801827480081469, 15.104412573075516,
    17.502307845873887, 19.987214495661885, 22.552163853123425,
    25.19122118273868, 27.89927138384089, 30.671860106080672,
    33.50507345013689, 36.39544520803305, 39.339884187199495,
    42.335616460753485, 45.38013889847691, 48.47118135183523,
    51.60667556776438, 54.78472939811232, 58.00360522298052,
    61.261701761002, 64.55753862700634, 67.88974313718154,
    71.25703896716801, 74.65823634883016};

__device__ inline int isqrt_k(int k) {
    int l = (int)sqrtf((float)k + 0.5f);
    while (l * l > k) --l;
    while ((l + 1) * (l + 1) <= k) ++l;
    return l;
}

// d^l_{m,n}(theta) via seed term (1 exp + 2 log) + exact ratio recurrence.
__device__ double wigner_d_rec(int l, int m, int n, double theta) {
    int an = n < 0 ? -n : n;
    int am = m < 0 ? -m : m;
    if (l < an || l < am) return 0.0;
    int kmin = max(0, n - m), kmax = min(l + n, l - m);
    if (kmax < kmin) return 0.0;
    double cb = cos(0.5 * theta), sb = sin(0.5 * theta);
    double pref = 0.5 * (LF[l + m] + LF[l - m] + LF[l + n] + LF[l - n]);
    double lterm = pref
        - (LF[l + n - kmin] + LF[kmin] + LF[m - n + kmin] + LF[l - m - kmin])
        + (double)(2 * l + n - m - 2 * kmin) * log(cb)
        + (double)(m - n + 2 * kmin) * log(sb);
    double term = exp(lterm);
    if ((m - n + kmin) & 1) term = -term;
    double r = (sb * sb) / (cb * cb);
    double acc = term;
    for (int k = kmin; k < kmax; ++k) {
        term *= -((double)((l + n - k) * (l - m - k)) * r)
                / ((double)((k + 1) * (m - n + k + 1)));
        acc += term;
    }
    return acc;
}

// K1: fused phi-DFT (blocks 0..511) + table generation (512..626)
//     + weight packing (627..674).
__global__ __launch_bounds__(512, 2) void k_phi_tables(const float* __restrict__ xr,
                                                       const float* __restrict__ xi,
                                                       __half2* __restrict__ F,
                                                       float* __restrict__ A_in,
                                                       float* __restrict__ A_out,
                                                       float* __restrict__ stats,
                                                       const float* __restrict__ kr,
                                                       const float* __restrict__ ki,
                                                       float4* __restrict__ W) {
    if (blockIdx.x >= 512) {
        if (blockIdx.x >= 627) {
            // pack kr/ki -> W[lis][u][dp] = (kr2d, kr2d+1, ki2d, ki2d+1)
            // 393,216 float4 over 48 blocks x 512 thr x 16 iters
            int e0 = (blockIdx.x - 627) * 512 + threadIdx.x;
            const float2* kr2 = (const float2*)kr;
            const float2* ki2 = (const float2*)ki;
#pragma unroll
            for (int j = 0; j < 16; ++j) {
                int e = e0 + j * 24576;
                int dp = e & 63, r = e >> 6;   // r = lis*64 + u, r < 6144
                float2 a = kr2[(size_t)r * 64 + dp];
                float2 b = ki2[(size_t)r * 64 + dp];
                W[e] = make_float4(a.x, a.y, b.x, b.y);
            }
            return;
        }
        int idx = (blockIdx.x - 512) * 512 + threadIdx.x;
        if (idx < 32768) {
            int t = idx & 63, k = (idx >> 6) & 255, i = idx >> 14;
            int l = isqrt_k(k);
            int m = k - l * l - l;
            double theta = ((double)t + 0.5) * PI_D / 64.0;
            double w = sin(theta) * (PI_D / 64.0) * (2.0 * PI_D / 64.0);
            double norm = sqrt((2.0 * l + 1.0) / (4.0 * PI_D));
            double d = wigner_d_rec(l, m, -i, theta);
            A_in[idx] = (float)(((m & 1) ? -1.0 : 1.0) * norm * w * d);
            return;
        }
        idx -= 32768;
        if (idx < 24576) {
            int t = idx & 31, k = (idx >> 5) & 255, s = idx >> 13;
            int l = isqrt_k(k);
            int m = k - l * l - l;
            double theta = ((double)t + 0.5) * PI_D / 32.0;
            double norm = sqrt((2.0 * l + 1.0) / (4.0 * PI_D));
            double d = wigner_d_rec(l, m, -s, theta);
            A_out[idx] = (float)(((m & 1) ? -1.0 : 1.0) * norm * d);
            return;
        }
        idx -= 24576;
        if (idx < 1152) stats[idx] = 0.f;
        return;
    }
    int bt = blockIdx.x;
    int iu = threadIdx.x & 127, mh = threadIdx.x >> 7;
    int mi0 = mh * 8;
    float2 acc[8], w[8], st[8];
#pragma unroll
    for (int j = 0; j < 8; ++j) {
        int m = mi0 + j - 15;
        float sy, sx;
        __sincosf(-(float)m * (float)(PI_D / 32.0), &sy, &sx);
        st[j] = make_float2(sx, sy);
        w[j] = make_float2(1.f, 0.f);
        acc[j] = make_float2(0.f, 0.f);
    }
    const float* xrb = xr + (size_t)bt * 8192 + iu;
    const float* xib = xi + (size_t)bt * 8192 + iu;
    for (int p = 0; p < 32; ++p) {
        float a  = xrb[(size_t)p * 128];
        float b  = xib[(size_t)p * 128];
        float a2 = xrb[(size_t)(p + 32) * 128];
        float b2 = xib[(size_t)(p + 32) * 128];
        float sar = a + a2, sai = b + b2;   // for even m
        float dar = a - a2, dai = b - b2;   // for odd m
#pragma unroll
        for (int j = 0; j < 8; ++j) {
            float ur = (j & 1) ? sar : dar;  // j odd -> m even
            float ui = (j & 1) ? sai : dai;
            acc[j].x += ur * w[j].x - ui * w[j].y;
            acc[j].y += ur * w[j].y + ui * w[j].x;
            float nx = w[j].x * st[j].x - w[j].y * st[j].y;
            w[j].y = w[j].x * st[j].y + w[j].y * st[j].x;
            w[j].x = nx;
        }
    }
    __half2* Fb = F + (size_t)bt * 31 * 128 + iu;
#pragma unroll
    for (int j = 0; j < 8; ++j) {
        int mi = mi0 + j;
        if (mi < 31) Fb[(size_t)mi * 128] = __float22half2_rn(acc[j]);
    }
}

// K2: theta contraction. grid (31, 8, 2) = (mi, b, iu-half); 256 threads =
// (iu_l 64) x (th 4). iu-half == spin index i, so only one A_in plane staged.
__global__ __launch_bounds__(256, 4) void k_theta_in(const __half2* __restrict__ F,
                                                     const float* __restrict__ A_in,
                                                     __half2* __restrict__ coeffs) {
    __shared__ float A[16][64];        // 4 KB, zero-padded below |m|
    __shared__ float2 red[2][16][64];  // 16 KB reduction buffer
    int mi = blockIdx.x, b = blockIdx.y, z = blockIdx.z;  // z = i
    int m = mi - 15;
    int am = m < 0 ? -m : m;
    int tid = threadIdx.x;
    for (int idx = tid; idx < 1024; idx += 256) {
        int j = idx >> 6, t = idx & 63;
        float v = 0.f;
        if (j >= am) v = A_in[((size_t)z * 256 + (j * j + j + m)) * 64 + t];
        A[j][t] = v;
    }
    __syncthreads();
    int iu_l = tid & 63, th = tid >> 6;
    int iu = z * 64 + iu_l;
    float2 acc[16];
#pragma unroll
    for (int j = 0; j < 16; ++j) acc[j] = make_float2(0.f, 0.f);
    const __half2* Fb = F + ((size_t)b * 64 * 31 + mi) * 128 + iu;
    for (int tt = 0; tt < 16; ++tt) {
        int t = th * 16 + tt;
        float2 f = __half22float2(Fb[(size_t)t * 31 * 128]);
#pragma unroll
        for (int j = 0; j < 16; ++j) {
            float a = A[j][t];
            acc[j].x += a * f.x;
            acc[j].y += a * f.y;
        }
    }
    if (th >= 2) {
#pragma unroll
        for (int j = 0; j < 16; ++j) red[th - 2][j][iu_l] = acc[j];
    }
    __syncthreads();
    if (th < 2) {
#pragma unroll
        for (int j = 0; j < 16; ++j) {
            float2 r = red[th][j][iu_l];
            acc[j].x += r.x;
            acc[j].y += r.y;
        }
    }
    __syncthreads();
    if (th == 1) {
#pragma unroll
        for (int j = 0; j < 16; ++j) red[0][j][iu_l] = acc[j];
    }
    __syncthreads();
    if (th == 0) {
#pragma unroll
        for (int j = 0; j < 16; ++j) {
            if (j >= am) {
                float2 r = red[0][j][iu_l];
                coeffs[((size_t)b * 256 + (j * j + j + m)) * 128 + iu] =
                    __float22half2_rn(make_float2(acc[j].x + r.x, acc[j].y + r.y));
            }
        }
    }
}

// K3: channel mix. grid (256, 2) = (k-swizzled, bq); 192 threads = (s 3)x(dp 64).
// Each block: 1 k x 4 b. XCD-chunked swizzle: XCD g = bid&7 owns k in
// [32g, 32g+32) so its l-slices (<=2.3MB) fit the private 4MB L2.
// Depth-1 prefetch: cur[4]/nxt[4] float4 = 32 VGPRs of weight state in flight
// (R17's 64-VGPR state + forced unroll spilled; WRITE_SIZE 416MB).
__global__ __launch_bounds__(192, 2) void k_mix(const __half2* __restrict__ coeffs,
                                                const float4* __restrict__ W,
                                                __half2* __restrict__ oc) {
    __shared__ float2 cs[4][128];  // [bb][iu], 4 KB (wave-uniform reads: broadcast)
    int bx = blockIdx.x;
    int k = ((bx & 7) << 5) + (bx >> 3);  // XCD-chunked k
    int b0 = blockIdx.y * 4;
    int tid = threadIdx.x;
    for (int idx = tid; idx < 512; idx += 192) {
        int bb = idx >> 7, iu = idx & 127;
        cs[bb][iu] =
            __half22float2(coeffs[((size_t)(b0 + bb) * 256 + k) * 128 + iu]);
    }
    __syncthreads();
    int s = tid >> 6, dp = tid & 63;
    int l = isqrt_k(k);
    float2 acc[4][2];
#pragma unroll
    for (int bb = 0; bb < 4; ++bb) {
        acc[bb][0] = make_float2(0.f, 0.f);
        acc[bb][1] = make_float2(0.f, 0.f);
    }
    const float4* W0 = W + (size_t)(6 * l + s) * 4096 + dp;  // i=0 slice
    const float4* W1 = W0 + (size_t)3 * 4096;                // i=1 slice
    float4 cur[4];
#pragma unroll
    for (int j = 0; j < 4; ++j) cur[j] = W0[(size_t)j * 64];
    for (int g = 0; g < 32; ++g) {
        float4 nxt[4];
        if (g < 31) {
            int iu0 = (g + 1) * 4;
            const float4* P = (iu0 < 64) ? (W0 + (size_t)iu0 * 64)
                                         : (W1 + (size_t)(iu0 - 64) * 64);
#pragma unroll
            for (int j = 0; j < 4; ++j) nxt[j] = P[(size_t)j * 64];
        }
#pragma unroll
        for (int j = 0; j < 4; ++j) {
            int iu = g * 4 + j;
            float2 wr = make_float2(cur[j].x, cur[j].y);
            float2 wi = make_float2(cur[j].z, cur[j].w);
#pragma unroll
            for (int bb = 0; bb < 4; ++bb) {
                float2 cv = cs[bb][iu];
                acc[bb][0].x += cv.x * wr.x - cv.y * wi.x;
                acc[bb][0].y += cv.x * wi.x + cv.y * wr.x;
                acc[bb][1].x += cv.x * wr.y - cv.y * wi.y;
                acc[bb][1].y += cv.x * wi.y + cv.y * wr.y;
            }
        }
        if (g < 31) {
#pragma unroll
            for (int j = 0; j < 4; ++j) cur[j] = nxt[j];
        }
    }
#pragma unroll
    for (int bb = 0; bb < 4; ++bb) {
        size_t o = ((size_t)(b0 + bb) * 256 + k) * 384 + s * 128 + 2 * dp;
        oc[o]     = __float22half2_rn(acc[bb][0]);
        oc[o + 1] = __float22half2_rn(acc[bb][1]);
    }
}

// K4: theta expansion + stats. grid (31, 8, 2) = (mi, b, sd-half); 192 threads.
__global__ __launch_bounds__(192, 4) void k_theta_out(const __half2* __restrict__ oc,
                                                      const float* __restrict__ A_out,
                                                      __half2* __restrict__ G,
                                                      float* __restrict__ ssr,
                                                      float* __restrict__ ssi,
                                                      float* __restrict__ ssq) {
    __shared__ float Ao[3][16][32];  // 6KB
    int mi = blockIdx.x, b = blockIdx.y, z = blockIdx.z;
    int m = mi - 15;
    int am = m < 0 ? -m : m;
    int tid = threadIdx.x;
    for (int idx = tid; idx < 1536; idx += 192) {
        int s = idx >> 9, j = (idx >> 5) & 15, t = idx & 31;
        float v = 0.f;
        if (j >= am) v = A_out[((size_t)s * 256 + (j * j + j + m)) * 32 + t];
        Ao[s][j][t] = v;
    }
    __syncthreads();
    int sd = z * 192 + tid;
    int s = sd >> 7;
    float2 c[16];
#pragma unroll
    for (int j = 0; j < 16; ++j) {
        c[j] = make_float2(0.f, 0.f);
        if (j >= am)
            c[j] = __half22float2(oc[((size_t)b * 256 + (j * j + j + m)) * 384 + sd]);
    }
    float sq = 0.f, sr = 0.f, si = 0.f;
    for (int t = 0; t < 32; ++t) {
        float fr = 0.f, fi = 0.f;
#pragma unroll
        for (int j = 0; j < 16; ++j) {
            float a = Ao[s][j][t];
            fr += a * c[j].x;
            fi += a * c[j].y;
        }
        G[(((size_t)b * 32 + t) * 31 + mi) * 384 + sd] =
            __float22half2_rn(make_float2(fr, fi));
        sq += fr * fr + fi * fi;
        if (mi == 15) { sr += fr; si += fi; }
    }
    atomicAdd(&ssq[sd], sq);
    if (mi == 15) {
        atomicAdd(&ssr[sd], sr);
        atomicAdd(&ssi[sd], si);
    }
}

// K5: phi synthesis + BN + gate, radix-2 folded. grid (256 bt, 2 sd-half),
// 192 threads. Rotation state (g[31]+st[31]) in registers; (192,2) caps 256.
__global__ __launch_bounds__(192, 2) void k_synth_final(const __half2* __restrict__ G,
                                                        const float* __restrict__ ssr,
                                                        const float* __restrict__ ssi,
                                                        const float* __restrict__ ssq,
                                                        const float* __restrict__ gamma,
                                                        const float* __restrict__ betar,
                                                        const float* __restrict__ betai,
                                                        const float* __restrict__ bias,
                                                        float* __restrict__ out) {
    int bt = blockIdx.x;
    int sd = blockIdx.y * 192 + threadIdx.x;
    int s = sd >> 7;
    float2 g[31], st[31];
#pragma unroll
    for (int mi = 0; mi < 31; ++mi) {
        g[mi] = __half22float2(G[((size_t)bt * 31 + mi) * 384 + sd]);
        float sy, sx;
        __sincosf((float)(mi - 15) * (float)(PI_D / 16.0), &sy, &sx);
        st[mi] = make_float2(sx, sy);
    }
    const float invN = 1.0f / 256.0f;
    float mur = 0.f, mui = 0.f;
    if (s == 0) { mur = ssr[sd] * invN; mui = ssi[sd] * invN; }
    float var = ssq[sd] * invN - (mur * mur + mui * mui);
    float scale = gamma[sd] / sqrtf(var + 1e-5f);
    float br = (s == 0) ? betar[sd] : 0.f;
    float bi = (s == 0) ? betai[sd] : 0.f;
    float bb = bias[sd];
    float* ob = out + (size_t)bt * 32 * 384 + sd;
    for (int p = 0; p < 16; ++p) {
        float fr = 0.f, fi = 0.f, fr2 = 0.f, fi2 = 0.f;
#pragma unroll
        for (int mi = 0; mi < 31; ++mi) {
            fr += g[mi].x;
            fi += g[mi].y;
            if (mi & 1) { fr2 += g[mi].x; fi2 += g[mi].y; }  // m even
            else        { fr2 -= g[mi].x; fi2 -= g[mi].y; }  // m odd
        }
        {
            float yr = (fr - mur) * scale + br;
            float yi = (fi - mui) * scale + bi;
            float mag = sqrtf(yr * yr + yi * yi);
            float f = fmaxf(mag + bb, 0.f) / (mag + 1e-6f);
            ob[(size_t)p * 384] = yr * f;
        }
        {
            float yr = (fr2 - mur) * scale + br;
            float yi = (fi2 - mui) * scale + bi;
            float mag = sqrtf(yr * yr + yi * yi);
            float f = fmaxf(mag + bb, 0.f) / (mag + 1e-6f);
            ob[(size_t)(p + 16) * 384] = yr * f;
        }
#pragma unroll
        for (int mi = 0; mi < 31; ++mi) {
            float nx = g[mi].x * st[mi].x - g[mi].y * st[mi].y;
            g[mi].y = g[mi].x * st[mi].y + g[mi].y * st[mi].x;
            g[mi].x = nx;
        }
    }
}

extern "C" void kernel_launch(void* const* d_in, const int* in_sizes, int n_in,
                              void* d_out, int out_size, void* d_ws, size_t ws_size,
                              hipStream_t stream) {
    const float* xr    = (const float*)d_in[0];
    const float* xi    = (const float*)d_in[1];
    const float* kr    = (const float*)d_in[2];
    const float* ki    = (const float*)d_in[3];
    const float* gamma = (const float*)d_in[4];
    const float* betar = (const float*)d_in[5];
    const float* betai = (const float*)d_in[6];
    const float* bias  = (const float*)d_in[7];
    float* out = (float*)d_out;

    char* ws = (char*)d_ws;
    float*   A_in   = (float*)(ws + OFF_A_IN);
    float*   A_out  = (float*)(ws + OFF_A_OUT);
    float*   stats  = (float*)(ws + OFF_STATS);
    float*   ssr    = stats;
    float*   ssi    = stats + 384;
    float*   ssq    = stats + 768;
    __half2* F      = (__half2*)(ws + OFF_R1);  // then oc (fp16)
    __half2* oc     = (__half2*)(ws + OFF_R1);
    __half2* coeffs = (__half2*)(ws + OFF_R2);  // then G (fp16)
    __half2* G      = (__half2*)(ws + OFF_R2);
    float4*  W      = (float4*)(ws + OFF_W);

    k_phi_tables<<<675, 512, 0, stream>>>(xr, xi, F, A_in, A_out, stats, kr, ki, W);
    k_theta_in<<<dim3(31, 8, 2), 256, 0, stream>>>(F, A_in, coeffs);
    k_mix<<<dim3(256, 2), 192, 0, stream>>>(coeffs, W, oc);
    k_theta_out<<<dim3(31, 8, 2), 192, 0, stream>>>(oc, A_out, G, ssr, ssi, ssq);
    k_synth_final<<<dim3(256, 2), 192, 0, stream>>>(G, ssr, ssi, ssq,
                                                    gamma, betar, betai, bias, out);
}